// Round 10
// baseline (252.069 us; speedup 1.0000x reference)
//
#include <hip/hip_runtime.h>
#include <hip/hip_bf16.h>

// GCN forward, MI355X. Round 10: scale-folded CSR (src-only, 4B) + XCD-
// sharded count/cursor atomics.
//
// Math: coef_e = dinv[src]*dinv[dst]. Store H'[i] = dinv[i]*H[i] (scaled in
// each producer's MFMA epilogue). Then agg(g) = relu(dinv[g]*(sum H'[src] +
// H'[g]) + bias) — NO per-edge coefficient, CSR = src index only.
//
//   memset(degs[8N]|desc|pooled|cnt)
//   cvt_we    : W->bf16 (W1..W4 frag-major) | batch->i32 | sharded degree
//               count (degs[blockIdx&7][d], XCD-local L2 atomics)
//   scan      : one dispatch, decoupled lookback over 8N transposed counts
//               -> row_ptr (8-segment rows), cursor[8][N], dinv
//   fill_gemm1: sharded CSR fill (4B src) | X@W1 MFMA (epilogue x dinv)
//   aggemm x3 : unweighted gather + self -> x dinv[g] + bias + relu -> LDS
//               -> MFMA (epilogue x dinv[node]) at the AGG's grid
//   agg_pool  : last gather -> x dinv[g]+bias+relu -> LDS pool -> atomics
//   final     : 64x16 @ 16x10 linear
//
// Lessons: R5 fuse at agg's grid, not gemm's. R7 no per-block fences.
// R9 CSR scatter writeback + random dinv loads + atomic ping-pong = 48us.
//
// MFMA 16x16x32_bf16 layouts (verified): A[m=l&15][k=(l>>4)*8+j] (k-contig);
// B frag f at Wf[f*1024+l*16..+16] = B[kb*32+(l>>4)*8+j][ct*16+(l&15)];
// C/D col=l&15, row=(l>>4)*4+reg.

#define N_GRAPHS 64
#define N_CLASSES 10

typedef short bf8_t __attribute__((ext_vector_type(8)));
typedef float f4_t  __attribute__((ext_vector_type(4)));

__device__ __forceinline__ float b2f(unsigned int u) {
  return __uint_as_float(u << 16);
}
__device__ __forceinline__ unsigned short f2b(float f) {
  unsigned int x = __float_as_uint(f);
  x += 0x7fffu + ((x >> 16) & 1u);   // RNE (finite values only)
  return (unsigned short)(x >> 16);
}

__device__ __forceinline__ void block_detect(const unsigned int* __restrict__ xraw,
    const unsigned int* __restrict__ eraw, int* f32, int* i64) {
  __shared__ int c_bf, c_nz;
  if (threadIdx.x == 0) { c_bf = 0; c_nz = 0; }
  __syncthreads();
  unsigned int d = xraw[threadIdx.x & 255];
  int e = (int)(((d & 0xffffu) >> 7) & 0xff);
  if (e >= 100 && e <= 140) atomicAdd(&c_bf, 1);
  if (eraw && threadIdx.x < 64 && eraw[2 * threadIdx.x + 1] != 0u) atomicAdd(&c_nz, 1);
  __syncthreads();
  *f32 = (c_bf < 150) ? 1 : 0;
  if (i64) *i64 = (c_nz == 0) ? 1 : 0;
}

struct WPtrs { const void* p[10]; };
static constexpr int WSEG[10] = {16384, 128, 8192, 64, 2048, 32, 512, 16, 160, 10};
static constexpr int WTOTAL   = 27546;
static constexpr int WOFF[10] = {0, 16384, 16512, 24704, 24768, 26816, 26848, 27360, 27376, 27536};

// blocks [0,BW): weights; [BW,BW+BB): batch; rest: sharded degree count.
__global__ __launch_bounds__(256) void cvt_we_kernel(
    const unsigned int* __restrict__ xraw, WPtrs wp, unsigned short* __restrict__ wc,
    const int* __restrict__ braw, int* __restrict__ b32,
    const int* __restrict__ eraw, int* __restrict__ degs,
    int BW, int BB, int n, int E) {
  int f32, i64;
  block_detect(xraw, (const unsigned int*)eraw, &f32, &i64);
  const int bid = blockIdx.x;
  if (bid < BW) {
    int i = bid * 256 + threadIdx.x;
    if (i >= WTOTAL) return;
    int off = i, s = 0;
    #pragma unroll
    for (int t = 0; t < 10; ++t) {
      if (s == 0 && off >= WSEG[t]) { off -= WSEG[t]; } else if (s == 0) { s = t + 1; }
    }
    s -= 1;
    int soff = off;
    if ((s & 1) == 0 && s <= 6) {           // W1..W4 -> fragment-major
      int KB, FOUT;
      if (s == 0)      { KB = 4; FOUT = 128; }
      else if (s == 2) { KB = 4; FOUT = 64; }
      else if (s == 4) { KB = 2; FOUT = 32; }
      else             { KB = 1; FOUT = 16; }
      int j = off & 7, l = (off >> 3) & 63, f = off >> 9;
      int ct = f / KB, kb = f - ct * KB;
      int k = kb * 32 + ((l >> 4) << 3) + j;
      int nn = ct * 16 + (l & 15);
      soff = k * FOUT + nn;
    }
    const void* p = wp.p[s];
    wc[WOFF[s] + off] = f32 ? f2b(((const float*)p)[soff])
                            : ((const unsigned short*)p)[soff];
  } else if (bid < BW + BB) {
    int i = (bid - BW) * 256 + threadIdx.x;
    if (i < n) b32[i] = i64 ? braw[2 * i] : braw[i];
  } else {
    int e = (bid - BW - BB) * 256 + threadIdx.x;
    if (e >= E) return;
    int d = i64 ? eraw[2 * (E + e)] : eraw[E + e];
    atomicAdd(&degs[(bid & 7) * n + d], 1);   // XCD-local shard
  }
}

// One-dispatch decoupled-lookback scan over M=8n transposed counts
// (flat i -> d=i>>3, s=i&7, value degs[s*n+d]). Emits row_ptr (8-segment
// rows), per-shard cursor (segment starts), dinv (group-of-8 rowsum).
__global__ __launch_bounds__(256) void scan_kernel(const int* __restrict__ degs,
    int* __restrict__ row_ptr, int* __restrict__ cursor, float* __restrict__ dinv,
    unsigned long long* __restrict__ desc, int n) {
  __shared__ int ws[4];
  __shared__ int s_total;
  __shared__ unsigned int s_prev;
  const int b = blockIdx.x, tid = threadIdx.x, lane = tid & 63, wv = tid >> 6;
  const int i = b * 256 + tid;
  const int d = i >> 3, s = i & 7;
  int v = (d < n) ? degs[s * n + d] : 0;
  int x = v;
  #pragma unroll
  for (int off = 1; off < 64; off <<= 1) {
    int y = __shfl_up(x, off, 64);
    if (lane >= off) x += y;
  }
  if (lane == 63) ws[wv] = x;
  __syncthreads();
  int wbase = 0;
  for (int w = 0; w < wv; ++w) wbase += ws[w];
  int incl = x + wbase;
  if (tid == 0) {
    int tot = ws[0] + ws[1] + ws[2] + ws[3];
    s_total = tot;
    unsigned long long st = (b == 0) ? (2ULL << 62) : (1ULL << 62);
    atomicExch(&desc[b], st | (unsigned long long)(unsigned int)tot);
    if (b == 0) s_prev = 0u;
  }
  __syncthreads();
  if (b > 0 && wv == 0) {
    unsigned int running = 0;
    int j = b - 1;
    while (true) {
      int idx = j - lane;
      unsigned long long dsc;
      if (idx >= 0) {
        do { dsc = atomicAdd(&desc[idx], 0ULL); } while ((dsc >> 62) == 0ULL);
      } else {
        dsc = (2ULL << 62);
      }
      unsigned long long ball = __ballot((dsc >> 62) == 2ULL);
      int fp = ball ? (__ffsll((unsigned long long)ball) - 1) : 64;
      unsigned int contrib = (lane <= fp) ? (unsigned int)(dsc & 0xffffffffULL) : 0u;
      #pragma unroll
      for (int o = 32; o; o >>= 1) contrib += __shfl_xor(contrib, o, 64);
      running += contrib;
      if (fp < 64) break;
      j -= 64;
    }
    if (lane == 0) {
      atomicExch(&desc[b], (2ULL << 62) |
                 (unsigned long long)(unsigned int)(running + (unsigned int)s_total));
      s_prev = running;
    }
  }
  __syncthreads();
  int tot = (int)s_prev + incl;
  int rs = v;                       // rowsum over the 8 shards (lane group)
  rs += __shfl_xor(rs, 1, 64);
  rs += __shfl_xor(rs, 2, 64);
  rs += __shfl_xor(rs, 4, 64);
  if (d < n) {
    cursor[s * n + d] = tot - v;
    if (s == 7) {
      row_ptr[d + 1] = tot;
      dinv[d] = rsqrtf((float)rs + 1.0f);
    }
  }
  if (i == 0) row_ptr[0] = 0;
}

// Merged: blocks [0,BE) sharded CSR fill (4B src only); rest X@W1 MFMA with
// dinv-scaled epilogue (writes H' = dinv*H).
__global__ __launch_bounds__(256) void fill_gemm1_kernel(
    const int* __restrict__ eraw, const unsigned int* __restrict__ xraw,
    int* __restrict__ cursor, const float* __restrict__ dinv,
    int* __restrict__ csr_src,
    const unsigned short* __restrict__ Wf, unsigned short* __restrict__ H,
    int BE, int n, int E) {
  int f32, i64;
  block_detect(xraw, (const unsigned int*)eraw, &f32, &i64);
  if (blockIdx.x < BE) {
    int e = blockIdx.x * 256 + threadIdx.x;
    if (e < E) {
      int s, d;
      if (i64) { s = eraw[2 * e]; d = eraw[2 * (E + e)]; }
      else     { s = eraw[e];     d = eraw[E + e]; }
      int pos = atomicAdd(&cursor[(blockIdx.x & 7) * n + d], 1);
      csr_src[pos] = s;
    }
    return;
  }
  const int b2 = blockIdx.x - BE;
  const int l = threadIdx.x & 63;
  const int r16 = l & 15, quad = l >> 4;
  const int m0 = (b2 * 4 + (threadIdx.x >> 6)) * 32;
  if (m0 >= n) return;
  bf8_t afrag[2][4];
  float dv[2][4];
  #pragma unroll
  for (int mt = 0; mt < 2; ++mt) {
    int node = m0 + mt * 16 + r16;
    int nc = node < n ? node : n - 1;
    #pragma unroll
    for (int r = 0; r < 4; ++r) {
      int nd = m0 + mt * 16 + quad * 4 + r;
      dv[mt][r] = dinv[nd < n ? nd : n - 1];
    }
    if (f32) {
      const float* xp = (const float*)xraw + (size_t)nc * 128 + quad * 8;
      #pragma unroll
      for (int kb = 0; kb < 4; ++kb) {
        const float4* p4 = (const float4*)(xp + kb * 32);
        float4 u0 = p4[0], u1 = p4[1];
        bf8_t a;
        a[0] = (short)f2b(u0.x); a[1] = (short)f2b(u0.y);
        a[2] = (short)f2b(u0.z); a[3] = (short)f2b(u0.w);
        a[4] = (short)f2b(u1.x); a[5] = (short)f2b(u1.y);
        a[6] = (short)f2b(u1.z); a[7] = (short)f2b(u1.w);
        afrag[mt][kb] = a;
      }
    } else {
      const unsigned short* xp = (const unsigned short*)xraw + (size_t)nc * 128 + quad * 8;
      #pragma unroll
      for (int kb = 0; kb < 4; ++kb)
        afrag[mt][kb] = *(const bf8_t*)(xp + kb * 32);
    }
  }
  #pragma unroll
  for (int ct = 0; ct < 8; ++ct) {
    bf8_t bfrag[4];
    #pragma unroll
    for (int kb = 0; kb < 4; ++kb)
      bfrag[kb] = *(const bf8_t*)(Wf + ((ct * 4 + kb) * 64 + l) * 8);
    #pragma unroll
    for (int mt = 0; mt < 2; ++mt) {
      f4_t acc = {0.f, 0.f, 0.f, 0.f};
      #pragma unroll
      for (int kb = 0; kb < 4; ++kb)
        acc = __builtin_amdgcn_mfma_f32_16x16x32_bf16(afrag[mt][kb], bfrag[kb], acc, 0, 0, 0);
      #pragma unroll
      for (int r = 0; r < 4; ++r) {
        int node = m0 + mt * 16 + quad * 4 + r;
        if (node < n)
          H[(size_t)node * 128 + ct * 16 + r16] = f2b(acc[r] * dv[mt][r]);
      }
    }
  }
}

// ---- generic per-lane vector of DW dwords ----
template<int DW> struct UVec { unsigned int d[DW]; };
template<int DW>
__device__ __forceinline__ UVec<DW> uload(const unsigned int* p) {
  UVec<DW> r;
  if constexpr (DW == 4) { uint4 v = *(const uint4*)p; r.d[0]=v.x; r.d[1]=v.y; r.d[2]=v.z; r.d[3]=v.w; }
  else if constexpr (DW == 2) { uint2 v = *(const uint2*)p; r.d[0]=v.x; r.d[1]=v.y; }
  else { r.d[0] = *p; }
  return r;
}
template<int DW>
__device__ __forceinline__ void ustore(unsigned int* p, const UVec<DW>& v) {
  if constexpr (DW == 4) { *(uint4*)p = make_uint4(v.d[0], v.d[1], v.d[2], v.d[3]); }
  else if constexpr (DW == 2) { *(uint2*)p = make_uint2(v.d[0], v.d[1]); }
  else { *p = v.d[0]; }
}

// Fused: unweighted gather(H') + self -> x dinv[g] + bias + relu -> LDS tile
// -> MFMA @ Wf -> Hout scaled by dinv[node] (H' for next layer).
template<int FIN, int FOUT, int LPG>
__global__ __launch_bounds__(256) void aggemm_kernel(
    const unsigned short* __restrict__ Hin,
    const int* __restrict__ row_ptr, const int* __restrict__ csr_src,
    const float* __restrict__ dinv, const unsigned short* __restrict__ bias,
    const unsigned short* __restrict__ Wf, unsigned short* __restrict__ Hout, int n) {
  constexpr int DW  = FIN / LPG / 2;
  constexpr int NPB = 256 / LPG;
  constexpr int LD  = FIN + 8;
  constexpr int KB  = FIN / 32;
  constexpr int CT  = FOUT / 16;
  constexpr int MT  = NPB / 16;
  __shared__ unsigned short T[NPB * LD];
  const int r = threadIdx.x / LPG, l = threadIdx.x % LPG;
  const int node0 = blockIdx.x * NPB;
  const int g = node0 + r;
  const unsigned int* H2 = (const unsigned int*)Hin;
  UVec<DW> o;
  #pragma unroll
  for (int d = 0; d < DW; ++d) o.d[d] = 0u;
  if (g < n) {
    float a[2 * DW];
    UVec<DW> hv = uload<DW>(H2 + (size_t)g * (FIN / 2) + l * DW);
    #pragma unroll
    for (int d = 0; d < DW; ++d) {          // self term H'[g]
      a[2*d]   = b2f(hv.d[d] & 0xffffu);
      a[2*d+1] = b2f(hv.d[d] >> 16);
    }
    const int e0 = row_ptr[g], e1 = row_ptr[g + 1];
    for (int base = e0; base < e1; base += LPG) {
      int cnt = e1 - base < LPG ? e1 - base : LPG;
      int my = csr_src[(base + l < e1) ? (base + l) : (e1 - 1)];
      for (int j = 0; j < cnt; ++j) {
        int s = __shfl(my, j, LPG);
        UVec<DW> v = uload<DW>(H2 + (size_t)s * (FIN / 2) + l * DW);
        #pragma unroll
        for (int d = 0; d < DW; ++d) {
          a[2*d]   += b2f(v.d[d] & 0xffffu);
          a[2*d+1] += b2f(v.d[d] >> 16);
        }
      }
    }
    float di = dinv[g];
    UVec<DW> bb = uload<DW>((const unsigned int*)bias + l * DW);
    #pragma unroll
    for (int d = 0; d < DW; ++d) {
      float lo = fmaxf(fmaf(a[2*d],   di, b2f(bb.d[d] & 0xffffu)), 0.f);
      float hi = fmaxf(fmaf(a[2*d+1], di, b2f(bb.d[d] >> 16)), 0.f);
      o.d[d] = (unsigned int)f2b(lo) | ((unsigned int)f2b(hi) << 16);
    }
  }
  ustore<DW>((unsigned int*)&T[r * LD + l * DW * 2], o);
  __syncthreads();
  const int w = threadIdx.x >> 6;
  if (w < MT * CT && node0 < n) {
    const int mt = w / CT, ct = w % CT;
    const int ll = threadIdx.x & 63;
    const int r16 = ll & 15, quad = ll >> 4;
    float dvv[4];
    #pragma unroll
    for (int rr = 0; rr < 4; ++rr) {
      int nd = node0 + mt * 16 + quad * 4 + rr;
      dvv[rr] = dinv[nd < n ? nd : n - 1];
    }
    bf8_t afrag[KB], bfrag[KB];
    #pragma unroll
    for (int kb = 0; kb < KB; ++kb) {
      afrag[kb] = *(const bf8_t*)(&T[(mt * 16 + r16) * LD + quad * 8 + kb * 32]);
      bfrag[kb] = *(const bf8_t*)(Wf + ((ct * KB + kb) * 64 + ll) * 8);
    }
    f4_t acc = {0.f, 0.f, 0.f, 0.f};
    #pragma unroll
    for (int kb = 0; kb < KB; ++kb)
      acc = __builtin_amdgcn_mfma_f32_16x16x32_bf16(afrag[kb], bfrag[kb], acc, 0, 0, 0);
    #pragma unroll
    for (int rr = 0; rr < 4; ++rr) {
      int node = node0 + mt * 16 + quad * 4 + rr;
      if (node < n)
        Hout[(size_t)node * FOUT + ct * 16 + r16] = f2b(acc[rr] * dvv[rr]);
    }
  }
}

// Fused last-layer agg + mean-pool. LPG=8, 32 nodes/block.
__global__ __launch_bounds__(256) void agg_pool_kernel(
    const unsigned short* __restrict__ Hin,
    const int* __restrict__ row_ptr, const int* __restrict__ csr_src,
    const float* __restrict__ dinv, const unsigned short* __restrict__ bias,
    const int* __restrict__ batch, float* __restrict__ pooled,
    float* __restrict__ cnt, int n) {
  __shared__ float acc[N_GRAPHS * 16];
  __shared__ float ccnt[N_GRAPHS];
  for (int i = threadIdx.x; i < N_GRAPHS * 16; i += 256) acc[i] = 0.f;
  if (threadIdx.x < N_GRAPHS) ccnt[threadIdx.x] = 0.f;
  __syncthreads();
  const int r = threadIdx.x >> 3, l = threadIdx.x & 7;
  const int g = blockIdx.x * 32 + r;
  if (g < n) {
    const unsigned int* H2 = (const unsigned int*)Hin;
    unsigned int hv = H2[(size_t)g * 8 + l];
    float a0 = b2f(hv & 0xffffu);          // self term H'[g]
    float a1 = b2f(hv >> 16);
    const int e0 = row_ptr[g], e1 = row_ptr[g + 1];
    for (int base = e0; base < e1; base += 8) {
      int cnt2 = e1 - base < 8 ? e1 - base : 8;
      int my = csr_src[(base + l < e1) ? (base + l) : (e1 - 1)];
      for (int j = 0; j < cnt2; ++j) {
        int s = __shfl(my, j, 8);
        unsigned int v = H2[(size_t)s * 8 + l];
        a0 += b2f(v & 0xffffu);
        a1 += b2f(v >> 16);
      }
    }
    float di = dinv[g];
    unsigned int bb = ((const unsigned int*)bias)[l];
    a0 = fmaxf(fmaf(a0, di, b2f(bb & 0xffffu)), 0.f);
    a1 = fmaxf(fmaf(a1, di, b2f(bb >> 16)), 0.f);
    int gb = batch[g];
    atomicAdd(&acc[gb * 16 + l * 2 + 0], a0);
    atomicAdd(&acc[gb * 16 + l * 2 + 1], a1);
    if (l == 0) atomicAdd(&ccnt[gb], 1.f);
  }
  __syncthreads();
  for (int i = threadIdx.x; i < N_GRAPHS * 16; i += 256)
    if (acc[i] != 0.f) atomicAdd(&pooled[i], acc[i]);
  if (threadIdx.x < N_GRAPHS && ccnt[threadIdx.x] != 0.f)
    atomicAdd(&cnt[threadIdx.x], ccnt[threadIdx.x]);
}

__global__ __launch_bounds__(256) void final_kernel(const float* __restrict__ pooled,
    const float* __restrict__ cnt, const unsigned short* __restrict__ wc,
    void* __restrict__ out, const unsigned int* __restrict__ xraw) {
  int f32;
  block_detect(xraw, nullptr, &f32, nullptr);
  int id = blockIdx.x * 256 + threadIdx.x;
  if (id >= N_GRAPHS * N_CLASSES) return;
  const unsigned short* Wlin = wc + WOFF[8];
  const unsigned short* blin = wc + WOFF[9];
  int g = id / N_CLASSES, c = id - g * N_CLASSES;
  float inv = 1.0f / fmaxf(cnt[g], 1.0f);
  float a = b2f(blin[c]);
  #pragma unroll
  for (int f = 0; f < 16; ++f)
    a = fmaf(pooled[g * 16 + f] * inv, b2f(Wlin[f * N_CLASSES + c]), a);
  if (f32) ((float*)out)[id] = a;
  else     ((unsigned short*)out)[id] = f2b(a);
}

extern "C" void kernel_launch(void* const* d_in, const int* in_sizes, int n_in,
                              void* d_out, int out_size, void* d_ws, size_t ws_size,
                              hipStream_t stream) {
  const unsigned int* xraw = (const unsigned int*)d_in[0];
  const int* eraw          = (const int*)d_in[1];
  const int* braw          = (const int*)d_in[2];

  const int N = in_sizes[2];
  const int E = in_sizes[1] / 2;
  const int nb2 = (8 * N + 255) / 256;     // scan blocks over 8N counts

  char* p = (char*)d_ws;
  auto alloc = [&](size_t bytes) -> void* {
    void* r = (void*)p;
    p += (bytes + 255) & ~(size_t)255;
    return r;
  };
  // zero region: degs[8N] | desc | pooled | cnt  (single memset)
  const size_t off_desc = ((size_t)8 * N * 4 + 255) & ~(size_t)255;
  const size_t off_pool = (off_desc + (size_t)nb2 * 8 + 255) & ~(size_t)255;
  const size_t ztotal   = off_pool + (N_GRAPHS * 16 + N_GRAPHS) * 4;
  char* zbase = (char*)alloc(ztotal);
  int*   degs   = (int*)zbase;
  unsigned long long* desc = (unsigned long long*)(zbase + off_desc);
  float* pooled = (float*)(zbase + off_pool);
  float* cntf   = pooled + N_GRAPHS * 16;

  int*   row_ptr  = (int*)  alloc((size_t)(N + 1) * 4);
  int*   cursor   = (int*)  alloc((size_t)8 * N * 4);
  float* dinv     = (float*)alloc((size_t)N * 4);
  int*   batch32  = (int*)  alloc((size_t)N * 4);
  int*   csr_src  = (int*)  alloc((size_t)E * 4);
  unsigned short* wcan  = (unsigned short*)alloc((size_t)WTOTAL * 2);
  unsigned short* hbufA = (unsigned short*)alloc((size_t)N * 128 * 2);
  unsigned short* hbufB = (unsigned short*)alloc((size_t)N * 128 * 2);

  hipMemsetAsync(zbase, 0, ztotal, stream);

  WPtrs wp;
  for (int i = 0; i < 10; ++i) wp.p[i] = d_in[3 + i];

  const int BW = (WTOTAL + 255) / 256;
  const int BB = (N + 255) / 256;
  const int BE = (E + 255) / 256;
  cvt_we_kernel<<<BW + BB + BE, 256, 0, stream>>>(xraw, wp, wcan, braw, batch32,
      eraw, degs, BW, BB, N, E);

  scan_kernel<<<nb2, 256, 0, stream>>>(degs, row_ptr, cursor, dinv, desc, N);

  const unsigned short* W1 = wcan + WOFF[0];
  const unsigned short* b1 = wcan + WOFF[1];
  const unsigned short* W2 = wcan + WOFF[2];
  const unsigned short* b2 = wcan + WOFF[3];
  const unsigned short* W3 = wcan + WOFF[4];
  const unsigned short* b3 = wcan + WOFF[5];
  const unsigned short* W4 = wcan + WOFF[6];
  const unsigned short* b4 = wcan + WOFF[7];

  const int G1 = (N + 127) / 128;
  fill_gemm1_kernel<<<BE + G1, 256, 0, stream>>>(eraw, xraw, cursor, dinv, csr_src,
      W1, hbufA, BE, N, E);

  aggemm_kernel<128, 64, 16><<<(N + 15) / 16, 256, 0, stream>>>(
      hbufA, row_ptr, csr_src, dinv, b1, W2, hbufB, N);
  aggemm_kernel<64, 32, 8><<<(N + 31) / 32, 256, 0, stream>>>(
      hbufB, row_ptr, csr_src, dinv, b2, W3, hbufA, N);
  aggemm_kernel<32, 16, 8><<<(N + 31) / 32, 256, 0, stream>>>(
      hbufA, row_ptr, csr_src, dinv, b3, W4, hbufB, N);
  agg_pool_kernel<<<(N + 31) / 32, 256, 0, stream>>>(hbufB, row_ptr, csr_src, dinv, b4,
      batch32, pooled, cntf, N);

  final_kernel<<<(N_GRAPHS * N_CLASSES + 255) / 256, 256, 0, stream>>>(pooled, cntf, wcan, d_out, xraw);
}

// Round 11
// 247.670 us; speedup vs baseline: 1.0178x; 1.0178x over previous
//
#include <hip/hip_runtime.h>
#include <hip/hip_bf16.h>

// GCN forward, MI355X. Round 11: R9's unsharded CSR build + R10's scale
// folding (best halves of both).
//
// Math: coef_e = dinv[src]*dinv[dst]. Store H'[i] = dinv[i]*H[i] (scaled in
// each producer's MFMA epilogue). agg(g) = relu(dinv[g]*(sum H'[src] +
// H'[g]) + bias) — no per-edge coefficient, CSR = 4B src index only,
// contiguous per row (minimal dirty-line writeback).
//
//   memset(deg|desc|pooled|cnt)
//   cvt_we    : W->bf16 (W1..W4 frag-major) | batch->i32 | degree count
//   scan      : one dispatch, decoupled lookback -> row_ptr/cursor/dinv
//   fill_gemm1: CSR fill (4B src, no dinv loads) | X@W1 MFMA (x dinv epi)
//   aggemm x3 : unweighted gather + self -> x dinv[g]+bias+relu -> LDS
//               -> MFMA (x dinv epi) at the AGG's grid
//   agg_pool  : last gather -> x dinv[g]+bias+relu -> LDS pool -> atomics
//   final     : 64x16 @ 16x10 linear
//
// Lessons: R5 fuse at agg's grid. R7 no per-block fences. R10 — scatter
// writeback ~ lines dirtied, NOT bytes: 8-way sharding split rows into 8
// tiny segments (8 lines/node) and erased the 2x entry-size win; keep CSR
// rows contiguous.
//
// MFMA 16x16x32_bf16 layouts (verified): A[m=l&15][k=(l>>4)*8+j] (k-contig);
// B frag f at Wf[f*1024+l*16..+16] = B[kb*32+(l>>4)*8+j][ct*16+(l&15)];
// C/D col=l&15, row=(l>>4)*4+reg.

#define N_GRAPHS 64
#define N_CLASSES 10

typedef short bf8_t __attribute__((ext_vector_type(8)));
typedef float f4_t  __attribute__((ext_vector_type(4)));

__device__ __forceinline__ float b2f(unsigned int u) {
  return __uint_as_float(u << 16);
}
__device__ __forceinline__ unsigned short f2b(float f) {
  unsigned int x = __float_as_uint(f);
  x += 0x7fffu + ((x >> 16) & 1u);   // RNE (finite values only)
  return (unsigned short)(x >> 16);
}

__device__ __forceinline__ void block_detect(const unsigned int* __restrict__ xraw,
    const unsigned int* __restrict__ eraw, int* f32, int* i64) {
  __shared__ int c_bf, c_nz;
  if (threadIdx.x == 0) { c_bf = 0; c_nz = 0; }
  __syncthreads();
  unsigned int d = xraw[threadIdx.x & 255];
  int e = (int)(((d & 0xffffu) >> 7) & 0xff);
  if (e >= 100 && e <= 140) atomicAdd(&c_bf, 1);
  if (eraw && threadIdx.x < 64 && eraw[2 * threadIdx.x + 1] != 0u) atomicAdd(&c_nz, 1);
  __syncthreads();
  *f32 = (c_bf < 150) ? 1 : 0;
  if (i64) *i64 = (c_nz == 0) ? 1 : 0;
}

struct WPtrs { const void* p[10]; };
static constexpr int WSEG[10] = {16384, 128, 8192, 64, 2048, 32, 512, 16, 160, 10};
static constexpr int WTOTAL   = 27546;
static constexpr int WOFF[10] = {0, 16384, 16512, 24704, 24768, 26816, 26848, 27360, 27376, 27536};

// blocks [0,BW): weights; [BW,BW+BB): batch; rest: degree count.
__global__ __launch_bounds__(256) void cvt_we_kernel(
    const unsigned int* __restrict__ xraw, WPtrs wp, unsigned short* __restrict__ wc,
    const int* __restrict__ braw, int* __restrict__ b32,
    const int* __restrict__ eraw, int* __restrict__ deg,
    int BW, int BB, int n, int E) {
  int f32, i64;
  block_detect(xraw, (const unsigned int*)eraw, &f32, &i64);
  const int bid = blockIdx.x;
  if (bid < BW) {
    int i = bid * 256 + threadIdx.x;
    if (i >= WTOTAL) return;
    int off = i, s = 0;
    #pragma unroll
    for (int t = 0; t < 10; ++t) {
      if (s == 0 && off >= WSEG[t]) { off -= WSEG[t]; } else if (s == 0) { s = t + 1; }
    }
    s -= 1;
    int soff = off;
    if ((s & 1) == 0 && s <= 6) {           // W1..W4 -> fragment-major
      int KB, FOUT;
      if (s == 0)      { KB = 4; FOUT = 128; }
      else if (s == 2) { KB = 4; FOUT = 64; }
      else if (s == 4) { KB = 2; FOUT = 32; }
      else             { KB = 1; FOUT = 16; }
      int j = off & 7, l = (off >> 3) & 63, f = off >> 9;
      int ct = f / KB, kb = f - ct * KB;
      int k = kb * 32 + ((l >> 4) << 3) + j;
      int nn = ct * 16 + (l & 15);
      soff = k * FOUT + nn;
    }
    const void* p = wp.p[s];
    wc[WOFF[s] + off] = f32 ? f2b(((const float*)p)[soff])
                            : ((const unsigned short*)p)[soff];
  } else if (bid < BW + BB) {
    int i = (bid - BW) * 256 + threadIdx.x;
    if (i < n) b32[i] = i64 ? braw[2 * i] : braw[i];
  } else {
    int e = (bid - BW - BB) * 256 + threadIdx.x;
    if (e >= E) return;
    int d = i64 ? eraw[2 * (E + e)] : eraw[E + e];
    atomicAdd(&deg[d], 1);
  }
}

// Single-dispatch decoupled-lookback scan (packed state|value atomics).
__global__ __launch_bounds__(256) void scan_kernel(const int* __restrict__ deg,
    int* __restrict__ row_ptr, int* __restrict__ cursor, float* __restrict__ dinv,
    unsigned long long* __restrict__ desc, int n) {
  __shared__ int ws[4];
  __shared__ int s_total;
  __shared__ unsigned int s_prev;
  const int b = blockIdx.x, tid = threadIdx.x, lane = tid & 63, wv = tid >> 6;
  const int i = b * 256 + tid;
  int v = (i < n) ? deg[i] : 0;
  int x = v;
  #pragma unroll
  for (int off = 1; off < 64; off <<= 1) {
    int y = __shfl_up(x, off, 64);
    if (lane >= off) x += y;
  }
  if (lane == 63) ws[wv] = x;
  __syncthreads();
  int wbase = 0;
  for (int w = 0; w < wv; ++w) wbase += ws[w];
  int incl = x + wbase;
  if (tid == 0) {
    int tot = ws[0] + ws[1] + ws[2] + ws[3];
    s_total = tot;
    unsigned long long st = (b == 0) ? (2ULL << 62) : (1ULL << 62);
    atomicExch(&desc[b], st | (unsigned long long)(unsigned int)tot);
    if (b == 0) s_prev = 0u;
  }
  __syncthreads();
  if (b > 0 && wv == 0) {
    unsigned int running = 0;
    int j = b - 1;
    while (true) {
      int idx = j - lane;
      unsigned long long dsc;
      if (idx >= 0) {
        do { dsc = atomicAdd(&desc[idx], 0ULL); } while ((dsc >> 62) == 0ULL);
      } else {
        dsc = (2ULL << 62);
      }
      unsigned long long ball = __ballot((dsc >> 62) == 2ULL);
      int fp = ball ? (__ffsll((unsigned long long)ball) - 1) : 64;
      unsigned int contrib = (lane <= fp) ? (unsigned int)(dsc & 0xffffffffULL) : 0u;
      #pragma unroll
      for (int o = 32; o; o >>= 1) contrib += __shfl_xor(contrib, o, 64);
      running += contrib;
      if (fp < 64) break;
      j -= 64;
    }
    if (lane == 0) {
      atomicExch(&desc[b], (2ULL << 62) |
                 (unsigned long long)(unsigned int)(running + (unsigned int)s_total));
      s_prev = running;
    }
  }
  __syncthreads();
  int tot = (int)s_prev + incl;
  if (i < n) {
    row_ptr[i + 1] = tot;
    cursor[i] = tot - v;
    dinv[i] = rsqrtf((float)v + 1.0f);
  }
  if (i == 0) row_ptr[0] = 0;
}

// Merged: blocks [0,BE) CSR fill (4B src, contiguous rows, no dinv loads);
// rest X@W1 MFMA with dinv-scaled epilogue (writes H' = dinv*H).
__global__ __launch_bounds__(256) void fill_gemm1_kernel(
    const int* __restrict__ eraw, const unsigned int* __restrict__ xraw,
    int* __restrict__ cursor, const float* __restrict__ dinv,
    int* __restrict__ csr_src,
    const unsigned short* __restrict__ Wf, unsigned short* __restrict__ H,
    int BE, int n, int E) {
  int f32, i64;
  block_detect(xraw, (const unsigned int*)eraw, &f32, &i64);
  if (blockIdx.x < BE) {
    int e = blockIdx.x * 256 + threadIdx.x;
    if (e < E) {
      int s, d;
      if (i64) { s = eraw[2 * e]; d = eraw[2 * (E + e)]; }
      else     { s = eraw[e];     d = eraw[E + e]; }
      int pos = atomicAdd(&cursor[d], 1);
      csr_src[pos] = s;
    }
    return;
  }
  const int b2 = blockIdx.x - BE;
  const int l = threadIdx.x & 63;
  const int r16 = l & 15, quad = l >> 4;
  const int m0 = (b2 * 4 + (threadIdx.x >> 6)) * 32;
  if (m0 >= n) return;
  bf8_t afrag[2][4];
  float dv[2][4];
  #pragma unroll
  for (int mt = 0; mt < 2; ++mt) {
    int node = m0 + mt * 16 + r16;
    int nc = node < n ? node : n - 1;
    #pragma unroll
    for (int r = 0; r < 4; ++r) {
      int nd = m0 + mt * 16 + quad * 4 + r;
      dv[mt][r] = dinv[nd < n ? nd : n - 1];
    }
    if (f32) {
      const float* xp = (const float*)xraw + (size_t)nc * 128 + quad * 8;
      #pragma unroll
      for (int kb = 0; kb < 4; ++kb) {
        const float4* p4 = (const float4*)(xp + kb * 32);
        float4 u0 = p4[0], u1 = p4[1];
        bf8_t a;
        a[0] = (short)f2b(u0.x); a[1] = (short)f2b(u0.y);
        a[2] = (short)f2b(u0.z); a[3] = (short)f2b(u0.w);
        a[4] = (short)f2b(u1.x); a[5] = (short)f2b(u1.y);
        a[6] = (short)f2b(u1.z); a[7] = (short)f2b(u1.w);
        afrag[mt][kb] = a;
      }
    } else {
      const unsigned short* xp = (const unsigned short*)xraw + (size_t)nc * 128 + quad * 8;
      #pragma unroll
      for (int kb = 0; kb < 4; ++kb)
        afrag[mt][kb] = *(const bf8_t*)(xp + kb * 32);
    }
  }
  #pragma unroll
  for (int ct = 0; ct < 8; ++ct) {
    bf8_t bfrag[4];
    #pragma unroll
    for (int kb = 0; kb < 4; ++kb)
      bfrag[kb] = *(const bf8_t*)(Wf + ((ct * 4 + kb) * 64 + l) * 8);
    #pragma unroll
    for (int mt = 0; mt < 2; ++mt) {
      f4_t acc = {0.f, 0.f, 0.f, 0.f};
      #pragma unroll
      for (int kb = 0; kb < 4; ++kb)
        acc = __builtin_amdgcn_mfma_f32_16x16x32_bf16(afrag[mt][kb], bfrag[kb], acc, 0, 0, 0);
      #pragma unroll
      for (int r = 0; r < 4; ++r) {
        int node = m0 + mt * 16 + quad * 4 + r;
        if (node < n)
          H[(size_t)node * 128 + ct * 16 + r16] = f2b(acc[r] * dv[mt][r]);
      }
    }
  }
}

// ---- generic per-lane vector of DW dwords ----
template<int DW> struct UVec { unsigned int d[DW]; };
template<int DW>
__device__ __forceinline__ UVec<DW> uload(const unsigned int* p) {
  UVec<DW> r;
  if constexpr (DW == 4) { uint4 v = *(const uint4*)p; r.d[0]=v.x; r.d[1]=v.y; r.d[2]=v.z; r.d[3]=v.w; }
  else if constexpr (DW == 2) { uint2 v = *(const uint2*)p; r.d[0]=v.x; r.d[1]=v.y; }
  else { r.d[0] = *p; }
  return r;
}
template<int DW>
__device__ __forceinline__ void ustore(unsigned int* p, const UVec<DW>& v) {
  if constexpr (DW == 4) { *(uint4*)p = make_uint4(v.d[0], v.d[1], v.d[2], v.d[3]); }
  else if constexpr (DW == 2) { *(uint2*)p = make_uint2(v.d[0], v.d[1]); }
  else { *p = v.d[0]; }
}

// Fused: unweighted gather(H') + self -> x dinv[g] + bias + relu -> LDS tile
// -> MFMA @ Wf -> Hout scaled by dinv[node] (H' for next layer).
template<int FIN, int FOUT, int LPG>
__global__ __launch_bounds__(256) void aggemm_kernel(
    const unsigned short* __restrict__ Hin,
    const int* __restrict__ row_ptr, const int* __restrict__ csr_src,
    const float* __restrict__ dinv, const unsigned short* __restrict__ bias,
    const unsigned short* __restrict__ Wf, unsigned short* __restrict__ Hout, int n) {
  constexpr int DW  = FIN / LPG / 2;
  constexpr int NPB = 256 / LPG;
  constexpr int LD  = FIN + 8;
  constexpr int KB  = FIN / 32;
  constexpr int CT  = FOUT / 16;
  constexpr int MT  = NPB / 16;
  __shared__ unsigned short T[NPB * LD];
  const int r = threadIdx.x / LPG, l = threadIdx.x % LPG;
  const int node0 = blockIdx.x * NPB;
  const int g = node0 + r;
  const unsigned int* H2 = (const unsigned int*)Hin;
  UVec<DW> o;
  #pragma unroll
  for (int d = 0; d < DW; ++d) o.d[d] = 0u;
  if (g < n) {
    float a[2 * DW];
    UVec<DW> hv = uload<DW>(H2 + (size_t)g * (FIN / 2) + l * DW);
    #pragma unroll
    for (int d = 0; d < DW; ++d) {          // self term H'[g]
      a[2*d]   = b2f(hv.d[d] & 0xffffu);
      a[2*d+1] = b2f(hv.d[d] >> 16);
    }
    const int e0 = row_ptr[g], e1 = row_ptr[g + 1];
    for (int base = e0; base < e1; base += LPG) {
      int cnt = e1 - base < LPG ? e1 - base : LPG;
      int my = csr_src[(base + l < e1) ? (base + l) : (e1 - 1)];
      for (int j = 0; j < cnt; ++j) {
        int s = __shfl(my, j, LPG);
        UVec<DW> v = uload<DW>(H2 + (size_t)s * (FIN / 2) + l * DW);
        #pragma unroll
        for (int d = 0; d < DW; ++d) {
          a[2*d]   += b2f(v.d[d] & 0xffffu);
          a[2*d+1] += b2f(v.d[d] >> 16);
        }
      }
    }
    float di = dinv[g];
    UVec<DW> bb = uload<DW>((const unsigned int*)bias + l * DW);
    #pragma unroll
    for (int d = 0; d < DW; ++d) {
      float lo = fmaxf(fmaf(a[2*d],   di, b2f(bb.d[d] & 0xffffu)), 0.f);
      float hi = fmaxf(fmaf(a[2*d+1], di, b2f(bb.d[d] >> 16)), 0.f);
      o.d[d] = (unsigned int)f2b(lo) | ((unsigned int)f2b(hi) << 16);
    }
  }
  ustore<DW>((unsigned int*)&T[r * LD + l * DW * 2], o);
  __syncthreads();
  const int w = threadIdx.x >> 6;
  if (w < MT * CT && node0 < n) {
    const int mt = w / CT, ct = w % CT;
    const int ll = threadIdx.x & 63;
    const int r16 = ll & 15, quad = ll >> 4;
    float dvv[4];
    #pragma unroll
    for (int rr = 0; rr < 4; ++rr) {
      int nd = node0 + mt * 16 + quad * 4 + rr;
      dvv[rr] = dinv[nd < n ? nd : n - 1];
    }
    bf8_t afrag[KB], bfrag[KB];
    #pragma unroll
    for (int kb = 0; kb < KB; ++kb) {
      afrag[kb] = *(const bf8_t*)(&T[(mt * 16 + r16) * LD + quad * 8 + kb * 32]);
      bfrag[kb] = *(const bf8_t*)(Wf + ((ct * KB + kb) * 64 + ll) * 8);
    }
    f4_t acc = {0.f, 0.f, 0.f, 0.f};
    #pragma unroll
    for (int kb = 0; kb < KB; ++kb)
      acc = __builtin_amdgcn_mfma_f32_16x16x32_bf16(afrag[kb], bfrag[kb], acc, 0, 0, 0);
    #pragma unroll
    for (int rr = 0; rr < 4; ++rr) {
      int node = node0 + mt * 16 + quad * 4 + rr;
      if (node < n)
        Hout[(size_t)node * FOUT + ct * 16 + r16] = f2b(acc[rr] * dvv[rr]);
    }
  }
}

// Fused last-layer agg + mean-pool. LPG=8, 32 nodes/block.
__global__ __launch_bounds__(256) void agg_pool_kernel(
    const unsigned short* __restrict__ Hin,
    const int* __restrict__ row_ptr, const int* __restrict__ csr_src,
    const float* __restrict__ dinv, const unsigned short* __restrict__ bias,
    const int* __restrict__ batch, float* __restrict__ pooled,
    float* __restrict__ cnt, int n) {
  __shared__ float acc[N_GRAPHS * 16];
  __shared__ float ccnt[N_GRAPHS];
  for (int i = threadIdx.x; i < N_GRAPHS * 16; i += 256) acc[i] = 0.f;
  if (threadIdx.x < N_GRAPHS) ccnt[threadIdx.x] = 0.f;
  __syncthreads();
  const int r = threadIdx.x >> 3, l = threadIdx.x & 7;
  const int g = blockIdx.x * 32 + r;
  if (g < n) {
    const unsigned int* H2 = (const unsigned int*)Hin;
    unsigned int hv = H2[(size_t)g * 8 + l];
    float a0 = b2f(hv & 0xffffu);          // self term H'[g]
    float a1 = b2f(hv >> 16);
    const int e0 = row_ptr[g], e1 = row_ptr[g + 1];
    for (int base = e0; base < e1; base += 8) {
      int cnt2 = e1 - base < 8 ? e1 - base : 8;
      int my = csr_src[(base + l < e1) ? (base + l) : (e1 - 1)];
      for (int j = 0; j < cnt2; ++j) {
        int s = __shfl(my, j, 8);
        unsigned int v = H2[(size_t)s * 8 + l];
        a0 += b2f(v & 0xffffu);
        a1 += b2f(v >> 16);
      }
    }
    float di = dinv[g];
    unsigned int bb = ((const unsigned int*)bias)[l];
    a0 = fmaxf(fmaf(a0, di, b2f(bb & 0xffffu)), 0.f);
    a1 = fmaxf(fmaf(a1, di, b2f(bb >> 16)), 0.f);
    int gb = batch[g];
    atomicAdd(&acc[gb * 16 + l * 2 + 0], a0);
    atomicAdd(&acc[gb * 16 + l * 2 + 1], a1);
    if (l == 0) atomicAdd(&ccnt[gb], 1.f);
  }
  __syncthreads();
  for (int i = threadIdx.x; i < N_GRAPHS * 16; i += 256)
    if (acc[i] != 0.f) atomicAdd(&pooled[i], acc[i]);
  if (threadIdx.x < N_GRAPHS && ccnt[threadIdx.x] != 0.f)
    atomicAdd(&cnt[threadIdx.x], ccnt[threadIdx.x]);
}

__global__ __launch_bounds__(256) void final_kernel(const float* __restrict__ pooled,
    const float* __restrict__ cnt, const unsigned short* __restrict__ wc,
    void* __restrict__ out, const unsigned int* __restrict__ xraw) {
  int f32;
  block_detect(xraw, nullptr, &f32, nullptr);
  int id = blockIdx.x * 256 + threadIdx.x;
  if (id >= N_GRAPHS * N_CLASSES) return;
  const unsigned short* Wlin = wc + WOFF[8];
  const unsigned short* blin = wc + WOFF[9];
  int g = id / N_CLASSES, c = id - g * N_CLASSES;
  float inv = 1.0f / fmaxf(cnt[g], 1.0f);
  float a = b2f(blin[c]);
  #pragma unroll
  for (int f = 0; f < 16; ++f)
    a = fmaf(pooled[g * 16 + f] * inv, b2f(Wlin[f * N_CLASSES + c]), a);
  if (f32) ((float*)out)[id] = a;
  else     ((unsigned short*)out)[id] = f2b(a);
}

extern "C" void kernel_launch(void* const* d_in, const int* in_sizes, int n_in,
                              void* d_out, int out_size, void* d_ws, size_t ws_size,
                              hipStream_t stream) {
  const unsigned int* xraw = (const unsigned int*)d_in[0];
  const int* eraw          = (const int*)d_in[1];
  const int* braw          = (const int*)d_in[2];

  const int N = in_sizes[2];
  const int E = in_sizes[1] / 2;
  const int nb = (N + 255) / 256;

  char* p = (char*)d_ws;
  auto alloc = [&](size_t bytes) -> void* {
    void* r = (void*)p;
    p += (bytes + 255) & ~(size_t)255;
    return r;
  };
  // zero region: deg | desc | pooled | cnt  (single memset)
  const size_t off_desc = ((size_t)N * 4 + 255) & ~(size_t)255;
  const size_t off_pool = (off_desc + (size_t)nb * 8 + 255) & ~(size_t)255;
  const size_t ztotal   = off_pool + (N_GRAPHS * 16 + N_GRAPHS) * 4;
  char* zbase = (char*)alloc(ztotal);
  int*   deg    = (int*)zbase;
  unsigned long long* desc = (unsigned long long*)(zbase + off_desc);
  float* pooled = (float*)(zbase + off_pool);
  float* cntf   = pooled + N_GRAPHS * 16;

  int*   row_ptr  = (int*)  alloc((size_t)(N + 1) * 4);
  int*   cursor   = (int*)  alloc((size_t)N * 4);
  float* dinv     = (float*)alloc((size_t)N * 4);
  int*   batch32  = (int*)  alloc((size_t)N * 4);
  int*   csr_src  = (int*)  alloc((size_t)E * 4);
  unsigned short* wcan  = (unsigned short*)alloc((size_t)WTOTAL * 2);
  unsigned short* hbufA = (unsigned short*)alloc((size_t)N * 128 * 2);
  unsigned short* hbufB = (unsigned short*)alloc((size_t)N * 128 * 2);

  hipMemsetAsync(zbase, 0, ztotal, stream);

  WPtrs wp;
  for (int i = 0; i < 10; ++i) wp.p[i] = d_in[3 + i];

  const int BW = (WTOTAL + 255) / 256;
  const int BB = nb;
  const int BE = (E + 255) / 256;
  cvt_we_kernel<<<BW + BB + BE, 256, 0, stream>>>(xraw, wp, wcan, braw, batch32,
      eraw, deg, BW, BB, N, E);

  scan_kernel<<<nb, 256, 0, stream>>>(deg, row_ptr, cursor, dinv, desc, N);

  const unsigned short* W1 = wcan + WOFF[0];
  const unsigned short* b1 = wcan + WOFF[1];
  const unsigned short* W2 = wcan + WOFF[2];
  const unsigned short* b2 = wcan + WOFF[3];
  const unsigned short* W3 = wcan + WOFF[4];
  const unsigned short* b3 = wcan + WOFF[5];
  const unsigned short* W4 = wcan + WOFF[6];
  const unsigned short* b4 = wcan + WOFF[7];

  const int G1 = (N + 127) / 128;
  fill_gemm1_kernel<<<BE + G1, 256, 0, stream>>>(eraw, xraw, cursor, dinv, csr_src,
      W1, hbufA, BE, N, E);

  aggemm_kernel<128, 64, 16><<<(N + 15) / 16, 256, 0, stream>>>(
      hbufA, row_ptr, csr_src, dinv, b1, W2, hbufB, N);
  aggemm_kernel<64, 32, 8><<<(N + 31) / 32, 256, 0, stream>>>(
      hbufB, row_ptr, csr_src, dinv, b2, W3, hbufA, N);
  aggemm_kernel<32, 16, 8><<<(N + 31) / 32, 256, 0, stream>>>(
      hbufA, row_ptr, csr_src, dinv, b3, W4, hbufB, N);
  agg_pool_kernel<<<(N + 31) / 32, 256, 0, stream>>>(hbufB, row_ptr, csr_src, dinv, b4,
      batch32, pooled, cntf, N);

  final_kernel<<<(N_GRAPHS * N_CLASSES + 255) / 256, 256, 0, stream>>>(pooled, cntf, wcan, d_out, xraw);
}